// Round 2
// baseline (56.174 us; speedup 1.0000x reference)
//
#include <hip/hip_runtime.h>
#include <math.h>

#define TWO_PI 6.2831853071795864769f

// ws layout (floats):
//   [0,     8192)  phi: 16 states x 256 amps x {re,im}
//   [8192, 10240)  H:   8 q x 16 x 16
//   [10240,42976)  y1:  32 x 1023
// total ~172 KB

// ---------------------------------------------------------------------------
// Register-resident statevector simulation.
// One wave (64 lanes) holds one 8-qubit state: lane owns amps k = lane*4+r,
// r in 0..3.  k bit p (p>=2) == lane bit (p-2); k bits 0,1 are the reg index.
// Qubit q lives at bit position p = 7-q.
// ---------------------------------------------------------------------------

__device__ __forceinline__ float2 shflx2(float2 a, int m) {
    return make_float2(__shfl_xor(a.x, m), __shfl_xor(a.y, m));
}

// in-register 2x2 gate on a pair (a = bit0 amp, b = bit1 amp); kind 0=RX 1=RY
__device__ __forceinline__ void pair_gate(float2& a, float2& b, float ch, float sh, int kind) {
    float2 na, nb;
    if (kind == 0) { // RX: n0 = ch*a + (0,-sh)*b ; n1 = (0,-sh)*a + ch*b
        na = make_float2(fmaf(ch, a.x, sh * b.y), fmaf(ch, a.y, -sh * b.x));
        nb = make_float2(fmaf(ch, b.x, sh * a.y), fmaf(ch, b.y, -sh * a.x));
    } else {         // RY: n0 = ch*a - sh*b ; n1 = sh*a + ch*b
        na = make_float2(fmaf(ch, a.x, -sh * b.x), fmaf(ch, a.y, -sh * b.y));
        nb = make_float2(fmaf(ch, b.x, sh * a.x), fmaf(ch, b.y, sh * a.y));
    }
    a = na; b = nb;
}

__device__ __forceinline__ void rot_gate(float2 v[4], int p, int lane, float ch, float sh, int kind) {
    if (p >= 2) {
        int m = 1 << (p - 2);
        bool b = (lane >> (p - 2)) & 1;
#pragma unroll
        for (int r = 0; r < 4; ++r) {
            float2 o = shflx2(v[r], m);
            if (kind == 0) {
                // RX symmetric: n = ch*self + (0,-sh)*other
                v[r] = make_float2(fmaf(ch, v[r].x, sh * o.y), fmaf(ch, v[r].y, -sh * o.x));
            } else {
                // RY: bit0 side: ch*self - sh*other ; bit1 side: ch*self + sh*other
                float sgn = b ? sh : -sh;
                v[r] = make_float2(fmaf(ch, v[r].x, sgn * o.x), fmaf(ch, v[r].y, sgn * o.y));
            }
        }
    } else if (p == 1) {
        pair_gate(v[0], v[2], ch, sh, kind);
        pair_gate(v[1], v[3], ch, sh, kind);
    } else {
        pair_gate(v[0], v[1], ch, sh, kind);
        pair_gate(v[2], v[3], ch, sh, kind);
    }
}

__device__ __forceinline__ void rz_gate(float2 v[4], int p, int lane, float ch, float sh) {
#pragma unroll
    for (int r = 0; r < 4; ++r) {
        int k = (lane << 2) | r;
        float s = ((k >> p) & 1) ? sh : -sh;   // phase (ch, s)
        v[r] = make_float2(fmaf(ch, v[r].x, -s * v[r].y), fmaf(ch, v[r].y, s * v[r].x));
    }
}

__device__ __forceinline__ void cnot_reg(float2 v[4], int pc, int pt, int lane) {
    if (pt >= 2) {               // target is a lane bit; control always lane bit here
        int m = 1 << (pt - 2);
        bool ctrl = (lane >> (pc - 2)) & 1;
#pragma unroll
        for (int r = 0; r < 4; ++r) {
            float2 o = shflx2(v[r], m);
            v[r] = ctrl ? o : v[r];
        }
    } else if (pt == 1) {        // pair (5,6): pc==2
        bool ctrl = (lane >> (pc - 2)) & 1;
        if (ctrl) {
            float2 t0 = v[0]; v[0] = v[2]; v[2] = t0;
            float2 t1 = v[1]; v[1] = v[3]; v[3] = t1;
        }
    } else {                     // pt == 0
        if (pc >= 2) {           // pair (0,7): ctrl lane bit
            bool ctrl = (lane >> (pc - 2)) & 1;
            if (ctrl) {
                float2 t0 = v[0]; v[0] = v[1]; v[1] = t0;
                float2 t1 = v[2]; v[2] = v[3]; v[3] = t1;
            }
        } else {                 // pair (6,7): ctrl = reg bit1 -> swap v2,v3
            float2 t = v[2]; v[2] = v[3]; v[3] = t;
        }
    }
}

// one ansatz layer: per wire j -> RX, CNOT, RY, CNOT, RZ (ring entanglement)
__device__ __forceinline__ void ansatz_reg(float2 v[4], const float* chs, const float* shs, int lane) {
#pragma unroll
    for (int j = 0; j < 8; ++j) {
        int p = 7 - j;
        int c = (j < 7) ? j : 0;
        int t = (j < 7) ? j + 1 : 7;
        int pc = 7 - c, pt = 7 - t;
        float ch = chs[j], sh = shs[j];
        rot_gate(v, p, lane, ch, sh, 0);
        cnot_reg(v, pc, pt, lane);
        rot_gate(v, p, lane, ch, sh, 1);
        cnot_reg(v, pc, pt, lane);
        rz_gate(v, p, lane, ch, sh);
    }
}

// K1: phi_S = ansatz(w2) ansatz(w1) B_S ansatz(w0) |0>, wave w handles S=w.
// Also initializes out[b] = bias (k_l2 atomically accumulates into it).
__global__ __launch_bounds__(1024) void k_sim(const float* wt, float2* phi,
                                              const float* db, float* out) {
    __shared__ float chs[24], shs[24];
    int tid = threadIdx.x;
    if (tid < 24) {
        float th = wt[tid];
        th = th - floorf(th / TWO_PI) * TWO_PI;   // jnp.mod(w, 2pi)
        float s, c;
        sincosf(0.5f * th, &s, &c);
        chs[tid] = c; shs[tid] = s;
    }
    if (tid < 32) out[tid] = db[0];
    __syncthreads();

    int w = tid >> 6;          // S index
    int lane = tid & 63;
    float2 v[4];
#pragma unroll
    for (int r = 0; r < 4; ++r) v[r] = make_float2(0.f, 0.f);
    if (lane == 0) v[0] = make_float2(1.f, 0.f);

    ansatz_reg(v, chs, shs, lane);

    // B_S: tensor of Y' = [[0,-1],[1,0]] on qubits in S (qubit q -> bit 7-q)
    int sbits = ((w & 1) << 7) | ((w & 2) << 5) | ((w & 4) << 3) | ((w & 8) << 1);
    int m = sbits >> 2;        // lane xor mask (sbits has no bits 0,1)
    float2 nv[4];
#pragma unroll
    for (int r = 0; r < 4; ++r) {
        float2 o = shflx2(v[r], m);
        int k = (lane << 2) | r;
        float sg = (__popc(sbits & ~k) & 1) ? -1.f : 1.f;
        nv[r] = make_float2(sg * o.x, sg * o.y);
    }
#pragma unroll
    for (int r = 0; r < 4; ++r) v[r] = nv[r];

    ansatz_reg(v, chs + 8, shs + 8, lane);
    ansatz_reg(v, chs + 16, shs + 16, lane);

#pragma unroll
    for (int r = 0; r < 4; ++r)
        phi[w * 256 + (lane << 2) + r] = v[r];
}

// K2: H_q[i][j] = sum_k z_q(k) Re(conj(phi_i[k]) phi_j[k]), one block per (i,j).
__global__ __launch_bounds__(64) void k_h(const float2* phi, float* H) {
    int i = blockIdx.x >> 4, j = blockIdx.x & 15;
    int lane = threadIdx.x;
    float acc[8] = {0.f, 0.f, 0.f, 0.f, 0.f, 0.f, 0.f, 0.f};
#pragma unroll
    for (int r = 0; r < 4; ++r) {
        int k = lane * 4 + r;
        float2 a = phi[i * 256 + k], b = phi[j * 256 + k];
        float p = a.x * b.x + a.y * b.y;
#pragma unroll
        for (int q = 0; q < 8; ++q)
            acc[q] += ((k >> (7 - q)) & 1) ? -p : p;
    }
#pragma unroll
    for (int q = 0; q < 8; ++q) {
#pragma unroll
        for (int off = 32; off >= 1; off >>= 1)
            acc[q] += __shfl_xor(acc[q], off);
    }
    if (lane == 0) {
#pragma unroll
        for (int q = 0; q < 8; ++q)
            H[q * 256 + i * 16 + j] = acc[q];
    }
}

// monomial vector: m[s] = prod_q (s>>q&1 ? sin(a_q/2) : cos(a_q/2))
__device__ __forceinline__ void build_m(const float* cc, const float* ss, float* m) {
    float m01[4] = {cc[0] * cc[1], ss[0] * cc[1], cc[0] * ss[1], ss[0] * ss[1]};
    float m23[4] = {cc[2] * cc[3], ss[2] * cc[3], cc[2] * ss[3], ss[2] * ss[3]};
#pragma unroll
    for (int u = 0; u < 16; ++u) m[u] = m01[u & 3] * m23[u >> 2];
}

// K3: layer-1, only <Z_0> needed. y1[b][s] = relu(m^T H0 m)
__global__ __launch_bounds__(256) void k_l1(const float* x, const float* H, float* y1) {
    __shared__ float H0[256];
    H0[threadIdx.x] = H[threadIdx.x];
    __syncthreads();
    int t = blockIdx.x * 256 + threadIdx.x;
    if (t >= 32 * 1023) return;
    int b = t / 1023;
    int s = t - b * 1023;
    float cc[4], ss[4];
#pragma unroll
    for (int i = 0; i < 4; ++i) {
        int l = s + i - 1;                      // PAD=1
        float a = (l >= 0 && l < 1024) ? x[b * 1024 + l] : 0.f;
        sincosf(0.5f * a, &ss[i], &cc[i]);
    }
    float m[16];
    build_m(cc, ss, m);
    float y = 0.f;
#pragma unroll
    for (int i2 = 0; i2 < 16; ++i2) {
        float ti = 0.f;
#pragma unroll
        for (int j2 = 0; j2 < 16; ++j2) ti = fmaf(H0[i2 * 16 + j2], m[j2], ti);
        y = fmaf(m[i2], ti, y);
    }
    y1[b * 1023 + s] = fmaxf(y, 0.f);
}

// K4: layer-2 + channel max-pool + dense partial, atomically added into out[b].
// 8 threads per window (one per q). 32 blocks per batch, 32 windows per block.
#define HSTRIDE 260   // 260 % 32 == 4 -> q*260 spreads 8 q over 8 banks; 16B aligned
__global__ __launch_bounds__(256) void k_l2(const float* y1, const float* dw,
                                            const float* H, float* out) {
    __shared__ float Hs[8 * HSTRIDE];
#pragma unroll
    for (int u = 0; u < 8; ++u) Hs[u * HSTRIDE + threadIdx.x] = H[u * 256 + threadIdx.x];
    __syncthreads();
    int blk = blockIdx.x;
    int b = blk >> 5;
    int c = blk & 31;
    int widx = c * 32 + (threadIdx.x >> 3);     // window in [0,1024), valid < 1022
    int q = threadIdx.x & 7;
    float yq = -1e30f;
    if (widx < 1022) {
        float cc[4], ss[4];
#pragma unroll
        for (int i = 0; i < 4; ++i) {
            int l = widx + i - 1;
            float a = (l >= 0 && l < 1023) ? y1[b * 1023 + l] : 0.f;
            sincosf(0.5f * a, &ss[i], &cc[i]);
        }
        float m[16];
        build_m(cc, ss, m);
        const float* Hq = &Hs[q * HSTRIDE];
        float y = 0.f;
#pragma unroll
        for (int i2 = 0; i2 < 16; ++i2) {
            float ti = 0.f;
#pragma unroll
            for (int j2 = 0; j2 < 16; ++j2) ti = fmaf(Hq[i2 * 16 + j2], m[j2], ti);
            y = fmaf(m[i2], ti, y);
        }
        yq = y;
    }
    // max over the 8 q-lanes of this window group
    yq = fmaxf(yq, __shfl_xor(yq, 1));
    yq = fmaxf(yq, __shfl_xor(yq, 2));
    yq = fmaxf(yq, __shfl_xor(yq, 4));
    float contrib = 0.f;
    if (q == 0 && widx < 1022) contrib = fmaxf(yq, 0.f) * dw[widx];
    __shared__ float red[256];
    red[threadIdx.x] = contrib;
    __syncthreads();
    for (int off = 128; off >= 1; off >>= 1) {
        if (threadIdx.x < off) red[threadIdx.x] += red[threadIdx.x + off];
        __syncthreads();
    }
    if (threadIdx.x == 0) atomicAdd(&out[b], red[0]);
}

extern "C" void kernel_launch(void* const* d_in, const int* in_sizes, int n_in,
                              void* d_out, int out_size, void* d_ws, size_t ws_size,
                              hipStream_t stream) {
    const float* x  = (const float*)d_in[0];   // (32,1024,1)
    const float* wt = (const float*)d_in[1];   // (3,8)
    const float* dw = (const float*)d_in[2];   // (1022,1)
    const float* db = (const float*)d_in[3];   // (1,)
    float* wsf = (float*)d_ws;
    float2* phi = (float2*)wsf;                // 8192 floats
    float* H    = wsf + 8192;                  // 2048 floats
    float* y1   = wsf + 10240;                 // 32736 floats
    float* out  = (float*)d_out;

    hipLaunchKernelGGL(k_sim, dim3(1),    dim3(1024), 0, stream, wt, phi, db, out);
    hipLaunchKernelGGL(k_h,   dim3(256),  dim3(64),   0, stream, (const float2*)phi, H);
    hipLaunchKernelGGL(k_l1,  dim3(128),  dim3(256),  0, stream, x, H, y1);
    hipLaunchKernelGGL(k_l2,  dim3(1024), dim3(256),  0, stream, y1, dw, H, out);
}

// Round 3
// 30.245 us; speedup vs baseline: 1.8573x; 1.8573x over previous
//
#include <hip/hip_runtime.h>
#include <math.h>

#define TWO_PI 6.2831853071795864769f

// ws layout (floats):
//   [0,     8192)  phi: 16 states x 256 amps x {re,im}
//   [8192, 10240)  H:   8 q x 16 x 16
//   [10240,42976)  y1:  32 x 1023
// total ~172 KB

// ---------------------------------------------------------------------------
// Register-resident statevector simulation, one wave per block (per CU).
// Lane owns amps k = lane*4+r, r in 0..3: k bit p (p>=2) == lane bit (p-2),
// k bits 1,0 == reg index bits. Qubit q lives at bit position p = 7-q.
//
// Gate fusion (derived analytically, both cases):
//   wire j<7 (rotation on CONTROL c=j, target t=j+1):
//     CNOT RY(th) CNOT = cos*I + sin*(Y'_c (x) X_t)
//     -> new[k] = ch*old[k] + sgn*old[k^M], M=(1<<pc)|(1<<pt), sgn=+sh iff k_c=1
//   wire j=7 (rotation on TARGET t=7, control c=0):
//     CNOT RY(th) CNOT = controlled-RY(+-th)
//     -> M=(1<<pt), sgn=+sh iff (k_c ^ k_t)=1
// Both: sgn = +sh iff popc(k & SB) odd, with SB as below.
// ---------------------------------------------------------------------------

__device__ __forceinline__ float2 shflx2(float2 a, int m) {
    return make_float2(__shfl_xor(a.x, m), __shfl_xor(a.y, m));
}

// generic mixing step: new[k] = ch*old[k] + coeff*old[k^M]
//   isRX: coeff = -i*sh (RX);  else coeff = (popc(k&SB)&1 ? +sh : -sh) (RY-like)
__device__ __forceinline__ void mixA(float2 v[4], int lane, int M, int SB,
                                     float ch, float sh, bool isRX) {
    int laneM = M >> 2, regM = M & 3;
    float2 o[4];
#pragma unroll
    for (int r = 0; r < 4; ++r) {
        float2 s = v[r ^ regM];
        o[r] = laneM ? shflx2(s, laneM) : s;
    }
#pragma unroll
    for (int r = 0; r < 4; ++r) {
        if (isRX) {
            v[r] = make_float2(fmaf(ch, v[r].x, sh * o[r].y),
                               fmaf(ch, v[r].y, -sh * o[r].x));
        } else {
            int k = (lane << 2) | r;
            float sg = (__popc(k & SB) & 1) ? sh : -sh;
            v[r] = make_float2(fmaf(ch, v[r].x, sg * o[r].x),
                               fmaf(ch, v[r].y, sg * o[r].y));
        }
    }
}

// one ansatz layer: per wire j -> RX, (CNOT RY CNOT fused), RZ
__device__ __forceinline__ void ansatz_reg(float2 v[4], const float* chs,
                                           const float* shs, int lane) {
#pragma unroll
    for (int j = 0; j < 8; ++j) {
        int p  = 7 - j;                        // rotation qubit position
        int pc = (j < 7) ? 7 - j : 7;          // control position
        int pt = (j < 7) ? 6 - j : 0;          // target position
        float ch = chs[j], sh = shs[j];
        mixA(v, lane, 1 << p, 0, ch, sh, true);                    // RX(wire j)
        int M  = (j < 7) ? ((1 << pc) | (1 << pt)) : (1 << pt);
        int SB = (j < 7) ? (1 << pc) : ((1 << pc) | (1 << pt));
        mixA(v, lane, M, SB, ch, sh, false);                       // fused CNOT RY CNOT
#pragma unroll
        for (int r = 0; r < 4; ++r) {                              // RZ(wire j), diagonal
            int k = (lane << 2) | r;
            float s = ((k >> p) & 1) ? sh : -sh;
            v[r] = make_float2(fmaf(ch, v[r].x, -s * v[r].y),
                               fmaf(ch, v[r].y, s * v[r].x));
        }
    }
}

// K1: phi_S = ansatz(w2) ansatz(w1) B_S ansatz(w0) |0>, one block (wave) per S.
// Block 0 also initializes out[b] = bias (k_l2 atomically accumulates into it).
__global__ __launch_bounds__(64) void k_sim(const float* wt, float2* phi,
                                            const float* db, float* out) {
    __shared__ float chs[24], shs[24];
    int lane = threadIdx.x;
    if (lane < 24) {
        float th = wt[lane];
        th = th - floorf(th / TWO_PI) * TWO_PI;   // jnp.mod(w, 2pi)
        float s, c;
        sincosf(0.5f * th, &s, &c);
        chs[lane] = c; shs[lane] = s;
    }
    if (blockIdx.x == 0 && lane < 32) out[lane] = db[0];
    __syncthreads();

    float2 v[4];
#pragma unroll
    for (int r = 0; r < 4; ++r) v[r] = make_float2(0.f, 0.f);
    if (lane == 0) v[0] = make_float2(1.f, 0.f);

    ansatz_reg(v, chs, shs, lane);

    // B_S: tensor of Y' = [[0,-1],[1,0]] on qubits in S (qubit q -> bit 7-q)
    int w = blockIdx.x;
    int sbits = ((w & 1) << 7) | ((w & 2) << 5) | ((w & 4) << 3) | ((w & 8) << 1);
    int m = sbits >> 2;        // pure lane-bit xor mask (sbits has no bits 0,1)
    float2 nv[4];
#pragma unroll
    for (int r = 0; r < 4; ++r) {
        float2 o = shflx2(v[r], m);
        int k = (lane << 2) | r;
        float sg = (__popc(sbits & ~k) & 1) ? -1.f : 1.f;
        nv[r] = make_float2(sg * o.x, sg * o.y);
    }
#pragma unroll
    for (int r = 0; r < 4; ++r) v[r] = nv[r];

    ansatz_reg(v, chs + 8, shs + 8, lane);
    ansatz_reg(v, chs + 16, shs + 16, lane);

#pragma unroll
    for (int r = 0; r < 4; ++r)
        phi[w * 256 + (lane << 2) + r] = v[r];
}

// K2: H_q[i][j] = sum_k z_q(k) Re(conj(phi_i[k]) phi_j[k]), one block per (i,j).
__global__ __launch_bounds__(64) void k_h(const float2* phi, float* H) {
    int i = blockIdx.x >> 4, j = blockIdx.x & 15;
    int lane = threadIdx.x;
    float acc[8] = {0.f, 0.f, 0.f, 0.f, 0.f, 0.f, 0.f, 0.f};
#pragma unroll
    for (int r = 0; r < 4; ++r) {
        int k = lane * 4 + r;
        float2 a = phi[i * 256 + k], b = phi[j * 256 + k];
        float p = a.x * b.x + a.y * b.y;
#pragma unroll
        for (int q = 0; q < 8; ++q)
            acc[q] += ((k >> (7 - q)) & 1) ? -p : p;
    }
#pragma unroll
    for (int q = 0; q < 8; ++q) {
#pragma unroll
        for (int off = 32; off >= 1; off >>= 1)
            acc[q] += __shfl_xor(acc[q], off);
    }
    if (lane == 0) {
#pragma unroll
        for (int q = 0; q < 8; ++q)
            H[q * 256 + i * 16 + j] = acc[q];
    }
}

// monomial vector: m[s] = prod_q (s>>q&1 ? sin(a_q/2) : cos(a_q/2))
__device__ __forceinline__ void build_m(const float* cc, const float* ss, float* m) {
    float m01[4] = {cc[0] * cc[1], ss[0] * cc[1], cc[0] * ss[1], ss[0] * ss[1]};
    float m23[4] = {cc[2] * cc[3], ss[2] * cc[3], cc[2] * ss[3], ss[2] * ss[3]};
#pragma unroll
    for (int u = 0; u < 16; ++u) m[u] = m01[u & 3] * m23[u >> 2];
}

// K3: layer-1, only <Z_0> needed. y1[b][s] = relu(m^T H0 m)
__global__ __launch_bounds__(256) void k_l1(const float* x, const float* H, float* y1) {
    __shared__ float H0[256];
    H0[threadIdx.x] = H[threadIdx.x];
    __syncthreads();
    int t = blockIdx.x * 256 + threadIdx.x;
    if (t >= 32 * 1023) return;
    int b = t / 1023;
    int s = t - b * 1023;
    float cc[4], ss[4];
#pragma unroll
    for (int i = 0; i < 4; ++i) {
        int l = s + i - 1;                      // PAD=1
        float a = (l >= 0 && l < 1024) ? x[b * 1024 + l] : 0.f;
        sincosf(0.5f * a, &ss[i], &cc[i]);
    }
    float m[16];
    build_m(cc, ss, m);
    float y = 0.f;
#pragma unroll
    for (int i2 = 0; i2 < 16; ++i2) {
        float ti = 0.f;
#pragma unroll
        for (int j2 = 0; j2 < 16; ++j2) ti = fmaf(H0[i2 * 16 + j2], m[j2], ti);
        y = fmaf(m[i2], ti, y);
    }
    y1[b * 1023 + s] = fmaxf(y, 0.f);
}

// K4: layer-2 + channel max-pool + dense partial, atomically added into out[b].
// 8 threads per window (one per q). 32 blocks per batch, 32 windows per block.
#define HSTRIDE 260   // 260 % 32 == 4 -> q*260 spreads 8 q over 8 banks; 16B aligned
__global__ __launch_bounds__(256) void k_l2(const float* y1, const float* dw,
                                            const float* H, float* out) {
    __shared__ float Hs[8 * HSTRIDE];
#pragma unroll
    for (int u = 0; u < 8; ++u) Hs[u * HSTRIDE + threadIdx.x] = H[u * 256 + threadIdx.x];
    __syncthreads();
    int blk = blockIdx.x;
    int b = blk >> 5;
    int c = blk & 31;
    int widx = c * 32 + (threadIdx.x >> 3);     // window in [0,1024), valid < 1022
    int q = threadIdx.x & 7;
    float yq = -1e30f;
    if (widx < 1022) {
        float cc[4], ss[4];
#pragma unroll
        for (int i = 0; i < 4; ++i) {
            int l = widx + i - 1;
            float a = (l >= 0 && l < 1023) ? y1[b * 1023 + l] : 0.f;
            sincosf(0.5f * a, &ss[i], &cc[i]);
        }
        float m[16];
        build_m(cc, ss, m);
        const float* Hq = &Hs[q * HSTRIDE];
        float y = 0.f;
#pragma unroll
        for (int i2 = 0; i2 < 16; ++i2) {
            float ti = 0.f;
#pragma unroll
            for (int j2 = 0; j2 < 16; ++j2) ti = fmaf(Hq[i2 * 16 + j2], m[j2], ti);
            y = fmaf(m[i2], ti, y);
        }
        yq = y;
    }
    // max over the 8 q-lanes of this window group
    yq = fmaxf(yq, __shfl_xor(yq, 1));
    yq = fmaxf(yq, __shfl_xor(yq, 2));
    yq = fmaxf(yq, __shfl_xor(yq, 4));
    float contrib = (q == 0 && widx < 1022) ? fmaxf(yq, 0.f) * dw[widx] : 0.f;
    // full-wave sum (non-q0 lanes contribute 0)
#pragma unroll
    for (int off = 1; off <= 32; off <<= 1) contrib += __shfl_xor(contrib, off);
    __shared__ float red[4];
    if ((threadIdx.x & 63) == 0) red[threadIdx.x >> 6] = contrib;
    __syncthreads();
    if (threadIdx.x == 0)
        atomicAdd(&out[b], red[0] + red[1] + red[2] + red[3]);
}

extern "C" void kernel_launch(void* const* d_in, const int* in_sizes, int n_in,
                              void* d_out, int out_size, void* d_ws, size_t ws_size,
                              hipStream_t stream) {
    const float* x  = (const float*)d_in[0];   // (32,1024,1)
    const float* wt = (const float*)d_in[1];   // (3,8)
    const float* dw = (const float*)d_in[2];   // (1022,1)
    const float* db = (const float*)d_in[3];   // (1,)
    float* wsf = (float*)d_ws;
    float2* phi = (float2*)wsf;                // 8192 floats
    float* H    = wsf + 8192;                  // 2048 floats
    float* y1   = wsf + 10240;                 // 32736 floats
    float* out  = (float*)d_out;

    hipLaunchKernelGGL(k_sim, dim3(16),   dim3(64),  0, stream, wt, phi, db, out);
    hipLaunchKernelGGL(k_h,   dim3(256),  dim3(64),  0, stream, (const float2*)phi, H);
    hipLaunchKernelGGL(k_l1,  dim3(128),  dim3(256), 0, stream, x, H, y1);
    hipLaunchKernelGGL(k_l2,  dim3(1024), dim3(256), 0, stream, y1, dw, H, out);
}

// Round 4
// 29.515 us; speedup vs baseline: 1.9033x; 1.0247x over previous
//
#include <hip/hip_runtime.h>
#include <math.h>

#define TWO_PI 6.2831853071795864769f

// ws layout (floats): [0, 2048) H: 8 q x 16 x 16.  (phi/y1 eliminated.)

// ---------------------------------------------------------------------------
// Register-resident statevector simulation, one wave simulates TWO states.
// Lane owns amps k = lane*4+r, r in 0..3: k bit p (p>=2) == lane bit (p-2),
// k bits 1,0 == reg index bits. Qubit q lives at bit position p = 7-q.
//
// Gate fusion (verified round 3, absmax 0.0):
//   wire j<7:  CNOT RY(th) CNOT = cos*I + sin*(Y'_c (x) X_t)
//     -> new[k] = ch*old[k] + sgn*old[k^M], M=(1<<pc)|(1<<pt), sgn=+sh iff k_c=1
//   wire j=7:  CNOT RY(th) CNOT = controlled-RY(+-th)
//     -> M=(1<<pt), sgn=+sh iff (k_c ^ k_t)=1
// ---------------------------------------------------------------------------

__device__ __forceinline__ float2 shflx2(float2 a, int m) {
    return make_float2(__shfl_xor(a.x, m), __shfl_xor(a.y, m));
}

// generic mixing step: new[k] = ch*old[k] + coeff*old[k^M]
//   isRX: coeff = -i*sh;  else coeff = (popc(k&SB)&1 ? +sh : -sh)
__device__ __forceinline__ void mixA(float2 v[4], int lane, int M, int SB,
                                     float ch, float sh, bool isRX) {
    int laneM = M >> 2, regM = M & 3;
    float2 o[4];
#pragma unroll
    for (int r = 0; r < 4; ++r) {
        float2 s = v[r ^ regM];
        o[r] = laneM ? shflx2(s, laneM) : s;
    }
#pragma unroll
    for (int r = 0; r < 4; ++r) {
        if (isRX) {
            v[r] = make_float2(fmaf(ch, v[r].x, sh * o[r].y),
                               fmaf(ch, v[r].y, -sh * o[r].x));
        } else {
            int k = (lane << 2) | r;
            float sg = (__popc(k & SB) & 1) ? sh : -sh;
            v[r] = make_float2(fmaf(ch, v[r].x, sg * o[r].x),
                               fmaf(ch, v[r].y, sg * o[r].y));
        }
    }
}

__device__ __forceinline__ void rz2(float2 v[4], float2 u[4], int lane, int p,
                                    float ch, float sh) {
#pragma unroll
    for (int r = 0; r < 4; ++r) {
        int k = (lane << 2) | r;
        float s = ((k >> p) & 1) ? sh : -sh;
        v[r] = make_float2(fmaf(ch, v[r].x, -s * v[r].y),
                           fmaf(ch, v[r].y, s * v[r].x));
        u[r] = make_float2(fmaf(ch, u[r].x, -s * u[r].y),
                           fmaf(ch, u[r].y, s * u[r].x));
    }
}

// one ansatz layer applied to BOTH states (independent chains -> 2-way ILP)
__device__ __forceinline__ void ansatz2(float2 v[4], float2 u[4],
                                        const float* chs, const float* shs, int lane) {
#pragma unroll
    for (int j = 0; j < 8; ++j) {
        int p  = 7 - j;
        int pc = (j < 7) ? 7 - j : 7;
        int pt = (j < 7) ? 6 - j : 0;
        float ch = chs[j], sh = shs[j];
        mixA(v, lane, 1 << p, 0, ch, sh, true);
        mixA(u, lane, 1 << p, 0, ch, sh, true);
        int M  = (j < 7) ? ((1 << pc) | (1 << pt)) : (1 << pt);
        int SB = (j < 7) ? (1 << pc) : ((1 << pc) | (1 << pt));
        mixA(v, lane, M, SB, ch, sh, false);
        mixA(u, lane, M, SB, ch, sh, false);
        rz2(v, u, lane, p, ch, sh);
    }
}

// B_S: tensor of Y' = [[0,-1],[1,0]] on qubits in S (qubit q -> bit 7-q)
__device__ __forceinline__ void applyB(float2 v[4], int S, int lane) {
    int sbits = ((S & 1) << 7) | ((S & 2) << 5) | ((S & 4) << 3) | ((S & 8) << 1);
    int m = sbits >> 2;          // pure lane-bit xor mask
    float2 nv[4];
#pragma unroll
    for (int r = 0; r < 4; ++r) {
        float2 o = shflx2(v[r], m);
        int k = (lane << 2) | r;
        float sg = (__popc(sbits & ~k) & 1) ? -1.f : 1.f;
        nv[r] = make_float2(sg * o.x, sg * o.y);
    }
#pragma unroll
    for (int r = 0; r < 4; ++r) v[r] = nv[r];
}

// K1: block (i,j) simulates phi_i and phi_j, emits H_q[i][j] for all 8 q.
// Block 0 also initializes out[b] = bias (k_l1l2 atomically accumulates).
__global__ __launch_bounds__(64) void k_simh(const float* wt, float* H,
                                             const float* db, float* out) {
    __shared__ float chs[24], shs[24];
    int lane = threadIdx.x;
    if (lane < 24) {
        float th = wt[lane];
        th = th - floorf(th / TWO_PI) * TWO_PI;   // jnp.mod(w, 2pi)
        float s, c;
        sincosf(0.5f * th, &s, &c);
        chs[lane] = c; shs[lane] = s;
    }
    if (blockIdx.x == 0 && lane < 32) out[lane] = db[0];
    __syncthreads();

    int i = blockIdx.x >> 4, j = blockIdx.x & 15;
    float2 v[4], u[4];
#pragma unroll
    for (int r = 0; r < 4; ++r) {
        v[r] = make_float2(0.f, 0.f);
        u[r] = make_float2(0.f, 0.f);
    }
    if (lane == 0) { v[0] = make_float2(1.f, 0.f); u[0] = make_float2(1.f, 0.f); }

    ansatz2(v, u, chs, shs, lane);
    applyB(v, i, lane);
    applyB(u, j, lane);
    ansatz2(v, u, chs + 8, shs + 8, lane);
    ansatz2(v, u, chs + 16, shs + 16, lane);

    // H_q[i][j] = sum_k z_q(k) Re(conj(phi_i[k]) phi_j[k])
    float acc[8] = {0.f, 0.f, 0.f, 0.f, 0.f, 0.f, 0.f, 0.f};
#pragma unroll
    for (int r = 0; r < 4; ++r) {
        int k = (lane << 2) | r;
        float p = v[r].x * u[r].x + v[r].y * u[r].y;
#pragma unroll
        for (int q = 0; q < 8; ++q)
            acc[q] += ((k >> (7 - q)) & 1) ? -p : p;
    }
#pragma unroll
    for (int q = 0; q < 8; ++q) {
#pragma unroll
        for (int off = 32; off >= 1; off >>= 1)
            acc[q] += __shfl_xor(acc[q], off);
    }
    if (lane == 0) {
#pragma unroll
        for (int q = 0; q < 8; ++q)
            H[q * 256 + i * 16 + j] = acc[q];
    }
}

// monomial vector: m[s] = prod_q (s>>q&1 ? sin(a_q/2) : cos(a_q/2))
__device__ __forceinline__ void build_m(const float* cc, const float* ss, float* m) {
    float m01[4] = {cc[0] * cc[1], ss[0] * cc[1], cc[0] * ss[1], ss[0] * ss[1]};
    float m23[4] = {cc[2] * cc[3], ss[2] * cc[3], cc[2] * ss[3], ss[2] * ss[3]};
#pragma unroll
    for (int u = 0; u < 16; ++u) m[u] = m01[u & 3] * m23[u >> 2];
}

// K2: fused layer-1 (halo recompute) + layer-2 + max-pool + dense partial.
// Block (b,c): windows widx = c*32 .. c*32+31, 8 q-lanes per window.
#define HSTRIDE 260   // q*260 % 32 banks = q*4 -> 8 q rows on 8 banks; 16B aligned
__global__ __launch_bounds__(256) void k_l1l2(const float* x, const float* H,
                                              const float* dw, float* out) {
    __shared__ float Hs[8 * HSTRIDE];
    __shared__ float ys[36];
    int tid = threadIdx.x;
#pragma unroll
    for (int r = 0; r < 8; ++r) Hs[r * HSTRIDE + tid] = H[r * 256 + tid];
    __syncthreads();

    int b = blockIdx.x >> 5;
    int c = blockIdx.x & 31;
    int base = c * 32 - 1;                      // y1 index of ys[0]

    // phase 1: y1 halo (35 values) into LDS; 0 outside [0,1023) = zero-pad
    if (tid < 35) {
        int s = base + tid;
        float y = 0.f;
        if (s >= 0 && s < 1023) {
            float cc[4], ss[4];
#pragma unroll
            for (int i = 0; i < 4; ++i) {
                int l = s + i - 1;              // PAD=1
                float a = (l >= 0 && l < 1024) ? x[b * 1024 + l] : 0.f;
                sincosf(0.5f * a, &ss[i], &cc[i]);
            }
            float m[16];
            build_m(cc, ss, m);
#pragma unroll
            for (int i2 = 0; i2 < 16; ++i2) {
                float ti = 0.f;
#pragma unroll
                for (int j2 = 0; j2 < 16; ++j2) ti = fmaf(Hs[i2 * 16 + j2], m[j2], ti);
                y = fmaf(m[i2], ti, y);
            }
            y = fmaxf(y, 0.f);                  // relu
        }
        ys[tid] = y;
    }
    __syncthreads();

    // phase 2: layer-2 quadratic form per (window, q)
    int widx = c * 32 + (tid >> 3);
    int q = tid & 7;
    float yq = -1e30f;
    if (widx < 1022) {
        float cc[4], ss[4];
#pragma unroll
        for (int i = 0; i < 4; ++i) {
            float a = ys[(tid >> 3) + i];
            sincosf(0.5f * a, &ss[i], &cc[i]);
        }
        float m[16];
        build_m(cc, ss, m);
        const float* Hq = &Hs[q * HSTRIDE];
        float y = 0.f;
#pragma unroll
        for (int i2 = 0; i2 < 16; ++i2) {
            float ti = 0.f;
#pragma unroll
            for (int j2 = 0; j2 < 16; ++j2) ti = fmaf(Hq[i2 * 16 + j2], m[j2], ti);
            y = fmaf(m[i2], ti, y);
        }
        yq = y;
    }
    // max over the 8 q-lanes of this window
    yq = fmaxf(yq, __shfl_xor(yq, 1));
    yq = fmaxf(yq, __shfl_xor(yq, 2));
    yq = fmaxf(yq, __shfl_xor(yq, 4));
    float contrib = (q == 0 && widx < 1022) ? fmaxf(yq, 0.f) * dw[widx] : 0.f;
#pragma unroll
    for (int off = 1; off <= 32; off <<= 1) contrib += __shfl_xor(contrib, off);
    __shared__ float red[4];
    if ((tid & 63) == 0) red[tid >> 6] = contrib;
    __syncthreads();
    if (tid == 0)
        atomicAdd(&out[b], red[0] + red[1] + red[2] + red[3]);
}

extern "C" void kernel_launch(void* const* d_in, const int* in_sizes, int n_in,
                              void* d_out, int out_size, void* d_ws, size_t ws_size,
                              hipStream_t stream) {
    const float* x  = (const float*)d_in[0];   // (32,1024,1)
    const float* wt = (const float*)d_in[1];   // (3,8)
    const float* dw = (const float*)d_in[2];   // (1022,1)
    const float* db = (const float*)d_in[3];   // (1,)
    float* H   = (float*)d_ws;                 // 2048 floats
    float* out = (float*)d_out;

    hipLaunchKernelGGL(k_simh, dim3(256),  dim3(64),  0, stream, wt, H, db, out);
    hipLaunchKernelGGL(k_l1l2, dim3(1024), dim3(256), 0, stream, x, H, dw, out);
}

// Round 5
// 28.477 us; speedup vs baseline: 1.9726x; 1.0364x over previous
//
#include <hip/hip_runtime.h>
#include <math.h>

#define TWO_PI 6.2831853071795864769f

// ws layout (floats):
//   [0,    2048)  H: 8 q x 16 x 16
//   [2048, 2720)  G: 8 q x 84 (81 trig-tensor coeffs + 3 zero pad)

// ---------------------------------------------------------------------------
// Register-resident statevector simulation, one wave simulates TWO states.
// Lane owns amps k = lane*4+r: k bit p (p>=2) == lane bit (p-2), k bits 1,0
// == reg index. Qubit q lives at bit position p = 7-q.
// Gate fusion (validated rounds 3/4, absmax 0.0):
//   wire j<7:  CNOT RY CNOT = cos*I + sin*(Y'_c (x) X_t)
//   wire j=7:  CNOT RY CNOT = controlled-RY(+-th)
// ---------------------------------------------------------------------------

__device__ __forceinline__ float2 shflx2(float2 a, int m) {
    return make_float2(__shfl_xor(a.x, m), __shfl_xor(a.y, m));
}

__device__ __forceinline__ void mixA(float2 v[4], int lane, int M, int SB,
                                     float ch, float sh, bool isRX) {
    int laneM = M >> 2, regM = M & 3;
    float2 o[4];
#pragma unroll
    for (int r = 0; r < 4; ++r) {
        float2 s = v[r ^ regM];
        o[r] = laneM ? shflx2(s, laneM) : s;
    }
#pragma unroll
    for (int r = 0; r < 4; ++r) {
        if (isRX) {
            v[r] = make_float2(fmaf(ch, v[r].x, sh * o[r].y),
                               fmaf(ch, v[r].y, -sh * o[r].x));
        } else {
            int k = (lane << 2) | r;
            float sg = (__popc(k & SB) & 1) ? sh : -sh;
            v[r] = make_float2(fmaf(ch, v[r].x, sg * o[r].x),
                               fmaf(ch, v[r].y, sg * o[r].y));
        }
    }
}

__device__ __forceinline__ void rz2(float2 v[4], float2 u[4], int lane, int p,
                                    float ch, float sh) {
#pragma unroll
    for (int r = 0; r < 4; ++r) {
        int k = (lane << 2) | r;
        float s = ((k >> p) & 1) ? sh : -sh;
        v[r] = make_float2(fmaf(ch, v[r].x, -s * v[r].y),
                           fmaf(ch, v[r].y, s * v[r].x));
        u[r] = make_float2(fmaf(ch, u[r].x, -s * u[r].y),
                           fmaf(ch, u[r].y, s * u[r].x));
    }
}

__device__ __forceinline__ void ansatz2(float2 v[4], float2 u[4],
                                        const float* chs, const float* shs, int lane) {
#pragma unroll
    for (int j = 0; j < 8; ++j) {
        int p  = 7 - j;
        int pc = (j < 7) ? 7 - j : 7;
        int pt = (j < 7) ? 6 - j : 0;
        float ch = chs[j], sh = shs[j];
        mixA(v, lane, 1 << p, 0, ch, sh, true);
        mixA(u, lane, 1 << p, 0, ch, sh, true);
        int M  = (j < 7) ? ((1 << pc) | (1 << pt)) : (1 << pt);
        int SB = (j < 7) ? (1 << pc) : ((1 << pc) | (1 << pt));
        mixA(v, lane, M, SB, ch, sh, false);
        mixA(u, lane, M, SB, ch, sh, false);
        rz2(v, u, lane, p, ch, sh);
    }
}

__device__ __forceinline__ void applyB(float2 v[4], int S, int lane) {
    int sbits = ((S & 1) << 7) | ((S & 2) << 5) | ((S & 4) << 3) | ((S & 8) << 1);
    int m = sbits >> 2;
    float2 nv[4];
#pragma unroll
    for (int r = 0; r < 4; ++r) {
        float2 o = shflx2(v[r], m);
        int k = (lane << 2) | r;
        float sg = (__popc(sbits & ~k) & 1) ? -1.f : 1.f;
        nv[r] = make_float2(sg * o.x, sg * o.y);
    }
#pragma unroll
    for (int r = 0; r < 4; ++r) v[r] = nv[r];
}

// K1: block (i,j) simulates phi_i and phi_j, emits H_q[i][j] for all 8 q.
// Block 0 also initializes out[b] = bias.
__global__ __launch_bounds__(64) void k_simh(const float* wt, float* H,
                                             const float* db, float* out) {
    __shared__ float chs[24], shs[24];
    int lane = threadIdx.x;
    if (lane < 24) {
        float th = wt[lane];
        th = th - floorf(th / TWO_PI) * TWO_PI;   // jnp.mod(w, 2pi)
        float s, c;
        sincosf(0.5f * th, &s, &c);
        chs[lane] = c; shs[lane] = s;
    }
    if (blockIdx.x == 0 && lane < 32) out[lane] = db[0];
    __syncthreads();

    int i = blockIdx.x >> 4, j = blockIdx.x & 15;
    float2 v[4], u[4];
#pragma unroll
    for (int r = 0; r < 4; ++r) {
        v[r] = make_float2(0.f, 0.f);
        u[r] = make_float2(0.f, 0.f);
    }
    if (lane == 0) { v[0] = make_float2(1.f, 0.f); u[0] = make_float2(1.f, 0.f); }

    ansatz2(v, u, chs, shs, lane);
    applyB(v, i, lane);
    applyB(u, j, lane);
    ansatz2(v, u, chs + 8, shs + 8, lane);
    ansatz2(v, u, chs + 16, shs + 16, lane);

    float acc[8] = {0.f, 0.f, 0.f, 0.f, 0.f, 0.f, 0.f, 0.f};
#pragma unroll
    for (int r = 0; r < 4; ++r) {
        int k = (lane << 2) | r;
        float p = v[r].x * u[r].x + v[r].y * u[r].y;
#pragma unroll
        for (int q = 0; q < 8; ++q)
            acc[q] += ((k >> (7 - q)) & 1) ? -p : p;
    }
#pragma unroll
    for (int q = 0; q < 8; ++q) {
#pragma unroll
        for (int off = 32; off >= 1; off >>= 1)
            acc[q] += __shfl_xor(acc[q], off);
    }
    if (lane == 0) {
#pragma unroll
        for (int q = 0; q < 8; ++q)
            H[q * 256 + i * 16 + j] = acc[q];
    }
}

// K2: trig tensor G_q[t], t = t0 + 3*t1 + 9*t2 + 27*t3, t_k in {0=1,1=cos,2=sin}.
// m_i m_j H_ij identity: c^2=(1+cos)/2, s^2=(1-cos)/2, cs=sin/2 =>
// G_q[t] = (1/16) * sum over 16 consistent (i,j) of (+-) H_q[i][j].
__global__ __launch_bounds__(256) void k_g(const float* H, float* G) {
    __shared__ float Hs[2048];
    int tid = threadIdx.x;
#pragma unroll
    for (int r = 0; r < 8; ++r) Hs[r * 256 + tid] = H[r * 256 + tid];
    __syncthreads();
    for (int e = tid; e < 672; e += 256) {
        int q = e / 84, t = e - q * 84;
        float acc = 0.f;
        if (t < 81) {
            int td0 = t % 3, td1 = (t / 3) % 3, td2 = (t / 9) % 3, td3 = t / 27;
            for (int cb = 0; cb < 16; ++cb) {
                int i = 0, j = 0; float sgn = 1.f;
                int td_[4] = {td0, td1, td2, td3};
#pragma unroll
                for (int k = 0; k < 4; ++k) {
                    int bk = (cb >> k) & 1;
                    if (td_[k] == 2) { i |= bk << k; j |= (1 - bk) << k; }
                    else { i |= bk << k; j |= bk << k;
                           if (td_[k] == 1 && bk) sgn = -sgn; }
                }
                acc += sgn * Hs[q * 256 + i * 16 + j];
            }
            acc *= 0.0625f;
        }
        G[e] = acc;
    }
}

// nested contraction: y = sum_t G[t] * f_{t0}(a0) f_{t1}(a1) f_{t2}(a2) f_{t3}(a3)
__device__ __forceinline__ float contract(const float* Gq,
        float c0, float s0, float c1, float s1,
        float c2, float s2, float c3, float s3) {
    float l3[27];
#pragma unroll
    for (int u = 0; u < 27; ++u)
        l3[u] = fmaf(Gq[u + 54], s3, fmaf(Gq[u + 27], c3, Gq[u]));
    float l2[9];
#pragma unroll
    for (int u = 0; u < 9; ++u)
        l2[u] = fmaf(l3[u + 18], s2, fmaf(l3[u + 9], c2, l3[u]));
    float l1[3];
#pragma unroll
    for (int u = 0; u < 3; ++u)
        l1[u] = fmaf(l2[u + 6], s1, fmaf(l2[u + 3], c1, l2[u]));
    return fmaf(l1[2], s0, fmaf(l1[1], c0, l1[0]));
}

// K3: fused layer-1 (halo) + layer-2 + max-pool + dense partial -> atomic out[b].
// Block (b,c): windows widx = c*32 .. c*32+31, 8 q-lanes per window.
// G rows stride 84: banks q*20 mod 32 all distinct -> conflict-free b128 reads.
__global__ __launch_bounds__(256) void k_l1l2(const float* x, const float* G,
                                              const float* dw, float* out) {
    __shared__ float Gs[672];
    __shared__ float xc[38], xs[38];   // sincos of x halo
    __shared__ float yc[35], ysn[35];  // sincos of y1 halo
    int tid = threadIdx.x;
    for (int e = tid; e < 672; e += 256) Gs[e] = G[e];

    int b = blockIdx.x >> 5;
    int c = blockIdx.x & 31;
    int base = c * 32 - 1;             // y1 index of halo slot 0

    if (tid < 38) {                    // x halo: l = base-1 .. base+36
        int l = base - 1 + tid;
        float a = (l >= 0 && l < 1024) ? x[b * 1024 + l] : 0.f;
        sincosf(a, &xs[tid], &xc[tid]);
    }
    __syncthreads();

    if (tid < 35) {                    // y1 halo: s = base .. base+34
        int s = base + tid;
        float y = 0.f;
        if (s >= 0 && s < 1023) {
            y = contract(Gs, xc[tid], xs[tid], xc[tid + 1], xs[tid + 1],
                         xc[tid + 2], xs[tid + 2], xc[tid + 3], xs[tid + 3]);
            y = fmaxf(y, 0.f);         // relu
        }
        sincosf(y, &ysn[tid], &yc[tid]);   // y=0 -> (sin,cos)=(0,1) = zero-pad
    }
    __syncthreads();

    int wi = tid >> 3;
    int q = tid & 7;
    int widx = c * 32 + wi;
    float yq = -1e30f;
    if (widx < 1022) {
        yq = contract(&Gs[q * 84], yc[wi], ysn[wi], yc[wi + 1], ysn[wi + 1],
                      yc[wi + 2], ysn[wi + 2], yc[wi + 3], ysn[wi + 3]);
    }
    // max over the 8 q-lanes of this window
    yq = fmaxf(yq, __shfl_xor(yq, 1));
    yq = fmaxf(yq, __shfl_xor(yq, 2));
    yq = fmaxf(yq, __shfl_xor(yq, 4));
    float contrib = (q == 0 && widx < 1022) ? fmaxf(yq, 0.f) * dw[widx] : 0.f;
#pragma unroll
    for (int off = 1; off <= 32; off <<= 1) contrib += __shfl_xor(contrib, off);
    __shared__ float red[4];
    if ((tid & 63) == 0) red[tid >> 6] = contrib;
    __syncthreads();
    if (tid == 0)
        atomicAdd(&out[b], red[0] + red[1] + red[2] + red[3]);
}

extern "C" void kernel_launch(void* const* d_in, const int* in_sizes, int n_in,
                              void* d_out, int out_size, void* d_ws, size_t ws_size,
                              hipStream_t stream) {
    const float* x  = (const float*)d_in[0];   // (32,1024,1)
    const float* wt = (const float*)d_in[1];   // (3,8)
    const float* dw = (const float*)d_in[2];   // (1022,1)
    const float* db = (const float*)d_in[3];   // (1,)
    float* H   = (float*)d_ws;                 // 2048 floats
    float* G   = (float*)d_ws + 2048;          // 672 floats
    float* out = (float*)d_out;

    hipLaunchKernelGGL(k_simh, dim3(256),  dim3(64),  0, stream, wt, H, db, out);
    hipLaunchKernelGGL(k_g,    dim3(1),    dim3(256), 0, stream, H, G);
    hipLaunchKernelGGL(k_l1l2, dim3(1024), dim3(256), 0, stream, x, G, dw, out);
}

// Round 6
// 25.778 us; speedup vs baseline: 2.1791x; 1.1047x over previous
//
#include <hip/hip_runtime.h>
#include <math.h>

#define TWO_PI 6.2831853071795864769f

// ws layout (floats):
//   [0,    2048)  H: 8 q x 16 x 16
//   [2048, 2976)  G: 8 q x 116 (27 float4 triplets {1,cos,sin,pad} per q)
//   [2976, 4000)  partials: 1024 (one per (b,c) block)

// ---------------------------------------------------------------------------
// Register-resident statevector sim, one wave simulates TWO states.
// Lane owns amps k = lane*4+r: k bit p (p>=2) == lane bit (p-2), k bits 1,0
// == reg index. Qubit q lives at bit position p = 7-q.
//
// Per-wire fusion (one cross-lane round per wire), derived + toy-verified:
//  j<7 (c=j rot wire, t=j+1):  U = (CNOT RY CNOT) RX =
//    psi'[k] = ch^2 psi[k] - i ch sh psi[k^pcb] + ch sh sA(k) psi[k^(pcb|ptb)]
//              - i sh^2 sA(k) psi[k^ptb],   sA=+1 iff k&pcb
//  j=7 (rot on target t=7, c=0): fully reg-local:
//    psi'[k] = (ch^2 - i sh^2 s7) psi[k] + ch sh (s7 - i) psi[k^1],
//    s7=+1 iff (k_bit7 ^ k_bit0)
// ---------------------------------------------------------------------------

__device__ __forceinline__ float2 shflx2(float2 a, int m) {
    return make_float2(__shfl_xor(a.x, m), __shfl_xor(a.y, m));
}

__device__ __forceinline__ void fused4(float2 v[4], int lane, int pcb, int ptb,
                                       float a2, float bb, float d2) {
    int M = pcb | ptb;
    int l1 = pcb >> 2, r1 = pcb & 3;
    int l2 = M >> 2,   r2 = M & 3;
    int l3 = ptb >> 2, r3 = ptb & 3;
    float2 o1[4], o2[4], o3[4];
#pragma unroll
    for (int r = 0; r < 4; ++r) {
        float2 s1 = v[r ^ r1]; o1[r] = l1 ? shflx2(s1, l1) : s1;
        float2 s2 = v[r ^ r2]; o2[r] = l2 ? shflx2(s2, l2) : s2;
        float2 s3 = v[r ^ r3]; o3[r] = l3 ? shflx2(s3, l3) : s3;
    }
#pragma unroll
    for (int r = 0; r < 4; ++r) {
        int k = (lane << 2) | r;
        float sA = (k & pcb) ? 1.f : -1.f;
        float bs = bb * sA, ds = d2 * sA;
        float nx = fmaf(a2, v[r].x, fmaf(bb, o1[r].y, fmaf(bs, o2[r].x,  ds * o3[r].y)));
        float ny = fmaf(a2, v[r].y, fmaf(-bb, o1[r].x, fmaf(bs, o2[r].y, -ds * o3[r].x)));
        v[r] = make_float2(nx, ny);
    }
}

__device__ __forceinline__ void wire7(float2 v[4], int lane, float a2, float bb, float d2) {
    float2 o[4];
#pragma unroll
    for (int r = 0; r < 4; ++r) o[r] = v[r ^ 1];
#pragma unroll
    for (int r = 0; r < 4; ++r) {
        int k = (lane << 2) | r;
        float s7 = (((k >> 7) ^ k) & 1) ? 1.f : -1.f;
        float Ax = a2, Ay = -d2 * s7, Bx = bb * s7, By = -bb;
        float nx = fmaf(Ax, v[r].x, fmaf(-Ay, v[r].y, fmaf(Bx, o[r].x, -By * o[r].y)));
        float ny = fmaf(Ax, v[r].y, fmaf( Ay, v[r].x, fmaf(Bx, o[r].y,  By * o[r].x)));
        v[r] = make_float2(nx, ny);
    }
}

__device__ __forceinline__ void rz2(float2 v[4], float2 u[4], int lane, int p,
                                    float ch, float sh) {
#pragma unroll
    for (int r = 0; r < 4; ++r) {
        int k = (lane << 2) | r;
        float s = ((k >> p) & 1) ? sh : -sh;
        v[r] = make_float2(fmaf(ch, v[r].x, -s * v[r].y),
                           fmaf(ch, v[r].y, s * v[r].x));
        u[r] = make_float2(fmaf(ch, u[r].x, -s * u[r].y),
                           fmaf(ch, u[r].y, s * u[r].x));
    }
}

__device__ __forceinline__ void ansatz2(float2 v[4], float2 u[4],
                                        const float* chs, const float* shs, int lane) {
#pragma unroll
    for (int j = 0; j < 7; ++j) {
        float ch = chs[j], sh = shs[j];
        float a2 = ch * ch, bb = ch * sh, d2 = sh * sh;
        int pcb = 1 << (7 - j), ptb = 1 << (6 - j);
        fused4(v, lane, pcb, ptb, a2, bb, d2);
        fused4(u, lane, pcb, ptb, a2, bb, d2);
        rz2(v, u, lane, 7 - j, ch, sh);
    }
    {
        float ch = chs[7], sh = shs[7];
        float a2 = ch * ch, bb = ch * sh, d2 = sh * sh;
        wire7(v, lane, a2, bb, d2);
        wire7(u, lane, a2, bb, d2);
        rz2(v, u, lane, 0, ch, sh);
    }
}

__device__ __forceinline__ void applyB(float2 v[4], int S, int lane) {
    int sbits = ((S & 1) << 7) | ((S & 2) << 5) | ((S & 4) << 3) | ((S & 8) << 1);
    int m = sbits >> 2;
    float2 nv[4];
#pragma unroll
    for (int r = 0; r < 4; ++r) {
        float2 o = shflx2(v[r], m);
        int k = (lane << 2) | r;
        float sg = (__popc(sbits & ~k) & 1) ? -1.f : 1.f;
        nv[r] = make_float2(sg * o.x, sg * o.y);
    }
#pragma unroll
    for (int r = 0; r < 4; ++r) v[r] = nv[r];
}

// K1: block (i,j) simulates phi_i and phi_j, emits H_q[i][j] for all 8 q.
__global__ __launch_bounds__(64) void k_simh(const float* wt, float* H) {
    __shared__ float chs[24], shs[24];
    int lane = threadIdx.x;
    if (lane < 24) {
        float th = wt[lane];
        th = th - floorf(th / TWO_PI) * TWO_PI;   // jnp.mod(w, 2pi)
        float s, c;
        sincosf(0.5f * th, &s, &c);
        chs[lane] = c; shs[lane] = s;
    }
    __syncthreads();

    int i = blockIdx.x >> 4, j = blockIdx.x & 15;
    float2 v[4], u[4];
#pragma unroll
    for (int r = 0; r < 4; ++r) {
        v[r] = make_float2(0.f, 0.f);
        u[r] = make_float2(0.f, 0.f);
    }
    if (lane == 0) { v[0] = make_float2(1.f, 0.f); u[0] = make_float2(1.f, 0.f); }

    ansatz2(v, u, chs, shs, lane);
    applyB(v, i, lane);
    applyB(u, j, lane);
    ansatz2(v, u, chs + 8, shs + 8, lane);
    ansatz2(v, u, chs + 16, shs + 16, lane);

    float acc[8] = {0.f, 0.f, 0.f, 0.f, 0.f, 0.f, 0.f, 0.f};
#pragma unroll
    for (int r = 0; r < 4; ++r) {
        int k = (lane << 2) | r;
        float p = v[r].x * u[r].x + v[r].y * u[r].y;
#pragma unroll
        for (int q = 0; q < 8; ++q)
            acc[q] += ((k >> (7 - q)) & 1) ? -p : p;
    }
#pragma unroll
    for (int q = 0; q < 8; ++q) {
#pragma unroll
        for (int off = 32; off >= 1; off >>= 1)
            acc[q] += __shfl_xor(acc[q], off);
    }
    if (lane == 0) {
#pragma unroll
        for (int q = 0; q < 8; ++q)
            H[q * 256 + i * 16 + j] = acc[q];
    }
}

// K2: trig tensor, triplet-packed: G[q*116 + u*4 + e] = Gold_q[t = u + 27*e],
// u in [0,27) indexes (t0,t1,t2); e in {0,1,2} is the t3 component {1,cos,sin}.
// Gold_q[t] = (1/16) sum over 16 consistent (i,j) of (+-) H_q[i][j].
__global__ __launch_bounds__(256) void k_g(const float* H, float* G) {
    __shared__ float Hs[2048];
    int tid = threadIdx.x;
#pragma unroll
    for (int r = 0; r < 8; ++r) Hs[r * 256 + tid] = H[r * 256 + tid];
    __syncthreads();
    for (int e = tid; e < 928; e += 256) {
        int q = e / 116, rem = e - q * 116;
        int u = rem >> 2, comp = rem & 3;
        float acc = 0.f;
        if (u < 27 && comp < 3) {
            int t = u + 27 * comp;
            int td_[4] = {t % 3, (t / 3) % 3, (t / 9) % 3, t / 27};
            for (int cb = 0; cb < 16; ++cb) {
                int i = 0, j = 0; float sgn = 1.f;
#pragma unroll
                for (int k = 0; k < 4; ++k) {
                    int bk = (cb >> k) & 1;
                    if (td_[k] == 2) { i |= bk << k; j |= (1 - bk) << k; }
                    else { i |= bk << k; j |= bk << k;
                           if (td_[k] == 1 && bk) sgn = -sgn; }
                }
                acc += sgn * Hs[q * 256 + i * 16 + j];
            }
            acc *= 0.0625f;
        }
        G[e] = acc;
    }
}

// nested contraction over triplet-packed row (27 x float4 LDS reads)
__device__ __forceinline__ float contract4(const float4* Tq,
        float c0, float s0, float c1, float s1,
        float c2, float s2, float c3, float s3) {
    float l3[27];
#pragma unroll
    for (int u = 0; u < 27; ++u) {
        float4 g = Tq[u];
        l3[u] = fmaf(g.z, s3, fmaf(g.y, c3, g.x));
    }
    float l2[9];
#pragma unroll
    for (int u = 0; u < 9; ++u)
        l2[u] = fmaf(l3[u + 18], s2, fmaf(l3[u + 9], c2, l3[u]));
    float l1[3];
#pragma unroll
    for (int u = 0; u < 3; ++u)
        l1[u] = fmaf(l2[u + 6], s1, fmaf(l2[u + 3], c1, l2[u]));
    return fmaf(l1[2], s0, fmaf(l1[1], c0, l1[0]));
}

// K3: fused layer-1 (halo) + layer-2 + max-pool + dense partial -> partials[blk].
// Block (b,c): windows widx = c*32 .. c*32+31, 8 q-lanes per window.
// G row stride 116 floats: b128 starts at (q*20+u*4) mod 32 -> conflict-free.
__global__ __launch_bounds__(256) void k_l1l2(const float* x, const float* G,
                                              const float* dw, float* partials) {
    __shared__ __align__(16) float Gs[928];
    __shared__ float xc[38], xs[38];   // sincos of x halo
    __shared__ float yc[35], ysn[35];  // sincos of y1 halo
    int tid = threadIdx.x;
    for (int e = tid; e < 928; e += 256) Gs[e] = G[e];

    int b = blockIdx.x >> 5;
    int c = blockIdx.x & 31;
    int base = c * 32 - 1;             // y1 index of halo slot 0

    if (tid < 38) {                    // x halo: l = base-1 .. base+36
        int l = base - 1 + tid;
        float a = (l >= 0 && l < 1024) ? x[b * 1024 + l] : 0.f;
        sincosf(a, &xs[tid], &xc[tid]);
    }
    __syncthreads();

    if (tid < 35) {                    // y1 halo: s = base .. base+34
        int s = base + tid;
        float y = 0.f;
        if (s >= 0 && s < 1023) {
            y = contract4((const float4*)Gs, xc[tid], xs[tid], xc[tid + 1], xs[tid + 1],
                          xc[tid + 2], xs[tid + 2], xc[tid + 3], xs[tid + 3]);
            y = fmaxf(y, 0.f);         // relu
        }
        sincosf(y, &ysn[tid], &yc[tid]);   // y=0 -> (sin,cos)=(0,1) = zero-pad
    }
    __syncthreads();

    int wi = tid >> 3;
    int q = tid & 7;
    int widx = c * 32 + wi;
    float yq = -1e30f;
    if (widx < 1022) {
        yq = contract4((const float4*)&Gs[q * 116],
                       yc[wi], ysn[wi], yc[wi + 1], ysn[wi + 1],
                       yc[wi + 2], ysn[wi + 2], yc[wi + 3], ysn[wi + 3]);
    }
    yq = fmaxf(yq, __shfl_xor(yq, 1));
    yq = fmaxf(yq, __shfl_xor(yq, 2));
    yq = fmaxf(yq, __shfl_xor(yq, 4));
    float contrib = (q == 0 && widx < 1022) ? fmaxf(yq, 0.f) * dw[widx] : 0.f;
#pragma unroll
    for (int off = 1; off <= 32; off <<= 1) contrib += __shfl_xor(contrib, off);
    __shared__ float red[4];
    if ((tid & 63) == 0) red[tid >> 6] = contrib;
    __syncthreads();
    if (tid == 0)
        partials[blockIdx.x] = red[0] + red[1] + red[2] + red[3];
}

// K4: out[b] = bias + sum_{c<32} partials[b*32+c].  One block, float4 + shfl.
__global__ __launch_bounds__(256) void k_out(const float* partials, const float* db,
                                             float* out) {
    int t = threadIdx.x;
    int b = t >> 3, g = t & 7;
    float4 p = ((const float4*)partials)[(b << 3) | g];
    float s = (p.x + p.y) + (p.z + p.w);
    s += __shfl_xor(s, 1);
    s += __shfl_xor(s, 2);
    s += __shfl_xor(s, 4);
    if (g == 0) out[b] = s + db[0];
}

extern "C" void kernel_launch(void* const* d_in, const int* in_sizes, int n_in,
                              void* d_out, int out_size, void* d_ws, size_t ws_size,
                              hipStream_t stream) {
    const float* x  = (const float*)d_in[0];   // (32,1024,1)
    const float* wt = (const float*)d_in[1];   // (3,8)
    const float* dw = (const float*)d_in[2];   // (1022,1)
    const float* db = (const float*)d_in[3];   // (1,)
    float* H        = (float*)d_ws;            // 2048 floats
    float* G        = (float*)d_ws + 2048;     // 928 floats
    float* partials = (float*)d_ws + 2976;     // 1024 floats
    float* out = (float*)d_out;

    hipLaunchKernelGGL(k_simh, dim3(256),  dim3(64),  0, stream, wt, H);
    hipLaunchKernelGGL(k_g,    dim3(1),    dim3(256), 0, stream, H, G);
    hipLaunchKernelGGL(k_l1l2, dim3(1024), dim3(256), 0, stream, x, G, dw, partials);
    hipLaunchKernelGGL(k_out,  dim3(1),    dim3(256), 0, stream, partials, db, out);
}

// Round 8
// 22.630 us; speedup vs baseline: 2.4823x; 1.1391x over previous
//
#include <hip/hip_runtime.h>
#include <math.h>

#define TWO_PI 6.2831853071795864769f

// ws layout (floats): [0, 2048) H: 8 q x 16 x 16.  (everything else is in-kernel)

// ---------------------------------------------------------------------------
// Register-resident statevector sim, one wave simulates TWO states.
// Lane owns amps k = lane*4+r: k bit p (p>=2) == lane bit (p-2), k bits 1,0
// == reg index. Qubit q lives at bit position p = 7-q.
// Per-wire fusion (one cross-lane round per wire), validated R6 (absmax 0.0):
//  j<7:  (CNOT RY CNOT) RX: 4-term gather, masks pcb, pcb|ptb, ptb
//  j=7:  fully register-local
// ---------------------------------------------------------------------------

__device__ __forceinline__ float2 shflx2(float2 a, int m) {
    return make_float2(__shfl_xor(a.x, m), __shfl_xor(a.y, m));
}

__device__ __forceinline__ void fused4(float2 v[4], int lane, int pcb, int ptb,
                                       float a2, float bb, float d2) {
    int M = pcb | ptb;
    int l1 = pcb >> 2, r1 = pcb & 3;
    int l2 = M >> 2,   r2 = M & 3;
    int l3 = ptb >> 2, r3 = ptb & 3;
    float2 o1[4], o2[4], o3[4];
#pragma unroll
    for (int r = 0; r < 4; ++r) {
        float2 s1 = v[r ^ r1]; o1[r] = l1 ? shflx2(s1, l1) : s1;
        float2 s2 = v[r ^ r2]; o2[r] = l2 ? shflx2(s2, l2) : s2;
        float2 s3 = v[r ^ r3]; o3[r] = l3 ? shflx2(s3, l3) : s3;
    }
#pragma unroll
    for (int r = 0; r < 4; ++r) {
        int k = (lane << 2) | r;
        float sA = (k & pcb) ? 1.f : -1.f;
        float bs = bb * sA, ds = d2 * sA;
        float nx = fmaf(a2, v[r].x, fmaf(bb, o1[r].y, fmaf(bs, o2[r].x,  ds * o3[r].y)));
        float ny = fmaf(a2, v[r].y, fmaf(-bb, o1[r].x, fmaf(bs, o2[r].y, -ds * o3[r].x)));
        v[r] = make_float2(nx, ny);
    }
}

__device__ __forceinline__ void wire7(float2 v[4], int lane, float a2, float bb, float d2) {
    float2 o[4];
#pragma unroll
    for (int r = 0; r < 4; ++r) o[r] = v[r ^ 1];
#pragma unroll
    for (int r = 0; r < 4; ++r) {
        int k = (lane << 2) | r;
        float s7 = (((k >> 7) ^ k) & 1) ? 1.f : -1.f;
        float Ax = a2, Ay = -d2 * s7, Bx = bb * s7, By = -bb;
        float nx = fmaf(Ax, v[r].x, fmaf(-Ay, v[r].y, fmaf(Bx, o[r].x, -By * o[r].y)));
        float ny = fmaf(Ax, v[r].y, fmaf( Ay, v[r].x, fmaf(Bx, o[r].y,  By * o[r].x)));
        v[r] = make_float2(nx, ny);
    }
}

__device__ __forceinline__ void rz2(float2 v[4], float2 u[4], int lane, int p,
                                    float ch, float sh) {
#pragma unroll
    for (int r = 0; r < 4; ++r) {
        int k = (lane << 2) | r;
        float s = ((k >> p) & 1) ? sh : -sh;
        v[r] = make_float2(fmaf(ch, v[r].x, -s * v[r].y),
                           fmaf(ch, v[r].y, s * v[r].x));
        u[r] = make_float2(fmaf(ch, u[r].x, -s * u[r].y),
                           fmaf(ch, u[r].y, s * u[r].x));
    }
}

__device__ __forceinline__ void ansatz2(float2 v[4], float2 u[4],
                                        const float* chs, const float* shs, int lane) {
#pragma unroll
    for (int j = 0; j < 7; ++j) {
        float ch = chs[j], sh = shs[j];
        float a2 = ch * ch, bb = ch * sh, d2 = sh * sh;
        int pcb = 1 << (7 - j), ptb = 1 << (6 - j);
        fused4(v, lane, pcb, ptb, a2, bb, d2);
        fused4(u, lane, pcb, ptb, a2, bb, d2);
        rz2(v, u, lane, 7 - j, ch, sh);
    }
    {
        float ch = chs[7], sh = shs[7];
        float a2 = ch * ch, bb = ch * sh, d2 = sh * sh;
        wire7(v, lane, a2, bb, d2);
        wire7(u, lane, a2, bb, d2);
        rz2(v, u, lane, 0, ch, sh);
    }
}

__device__ __forceinline__ void applyB(float2 v[4], int S, int lane) {
    int sbits = ((S & 1) << 7) | ((S & 2) << 5) | ((S & 4) << 3) | ((S & 8) << 1);
    int m = sbits >> 2;
    float2 nv[4];
#pragma unroll
    for (int r = 0; r < 4; ++r) {
        float2 o = shflx2(v[r], m);
        int k = (lane << 2) | r;
        float sg = (__popc(sbits & ~k) & 1) ? -1.f : 1.f;
        nv[r] = make_float2(sg * o.x, sg * o.y);
    }
#pragma unroll
    for (int r = 0; r < 4; ++r) v[r] = nv[r];
}

// K1: block (i,j) simulates phi_i and phi_j, emits H_q[i][j] for all 8 q.
// Block 0 also initializes out[b] = bias (k_main atomically accumulates).
__global__ __launch_bounds__(64) void k_simh(const float* wt, float* H,
                                             const float* db, float* out) {
    __shared__ float chs[24], shs[24];
    int lane = threadIdx.x;
    if (lane < 24) {
        float th = wt[lane];
        th = th - floorf(th / TWO_PI) * TWO_PI;   // jnp.mod(w, 2pi)
        float s, c;
        sincosf(0.5f * th, &s, &c);
        chs[lane] = c; shs[lane] = s;
    }
    if (blockIdx.x == 0 && lane < 32) out[lane] = db[0];
    __syncthreads();

    int i = blockIdx.x >> 4, j = blockIdx.x & 15;
    float2 v[4], u[4];
#pragma unroll
    for (int r = 0; r < 4; ++r) {
        v[r] = make_float2(0.f, 0.f);
        u[r] = make_float2(0.f, 0.f);
    }
    if (lane == 0) { v[0] = make_float2(1.f, 0.f); u[0] = make_float2(1.f, 0.f); }

    ansatz2(v, u, chs, shs, lane);
    applyB(v, i, lane);
    applyB(u, j, lane);
    ansatz2(v, u, chs + 8, shs + 8, lane);
    ansatz2(v, u, chs + 16, shs + 16, lane);

    float acc[8] = {0.f, 0.f, 0.f, 0.f, 0.f, 0.f, 0.f, 0.f};
#pragma unroll
    for (int r = 0; r < 4; ++r) {
        int k = (lane << 2) | r;
        float p = v[r].x * u[r].x + v[r].y * u[r].y;
#pragma unroll
        for (int q = 0; q < 8; ++q)
            acc[q] += ((k >> (7 - q)) & 1) ? -p : p;
    }
#pragma unroll
    for (int q = 0; q < 8; ++q) {
#pragma unroll
        for (int off = 32; off >= 1; off >>= 1)
            acc[q] += __shfl_xor(acc[q], off);
    }
    if (lane == 0) {
#pragma unroll
        for (int q = 0; q < 8; ++q)
            H[q * 256 + i * 16 + j] = acc[q];
    }
}

// ---------------------------------------------------------------------------
// K2: everything else, one block per (b, segment-of-128-windows).
// Phases: load H + x-halo sincos + dw slice | build G in LDS | y1 halo (131)
// | 4 windows per lane, G reads hoisted to registers | pool + dense + atomic.
// G row stride 116 floats: b128 reads at (q*20 + u*4) mod 32 -> conflict-free.
// ---------------------------------------------------------------------------
#define GSTRIDE 116

__global__ __launch_bounds__(256, 1) void k_main(const float* x, const float* H,
                                                 const float* dw, float* out) {
    __shared__ __align__(16) float Hs[2048];
    __shared__ __align__(16) float Gs[8 * GSTRIDE];   // 928 floats
    __shared__ float2 xcs[134];
    __shared__ float2 ycs[131];
    __shared__ float dwc[128];
    __shared__ float red[4];
    int tid = threadIdx.x;
    int b = blockIdx.x >> 3, seg = blockIdx.x & 7;
    int W0 = seg << 7;                 // first window of this segment

    // phase 0: H -> LDS (float4), x halo sincos, dw slice
    {
        const float4* H4 = (const float4*)H;
        float4* Hs4 = (float4*)Hs;
        Hs4[tid] = H4[tid];
        Hs4[tid + 256] = H4[tid + 256];
    }
    if (tid < 134) {                   // x positions l = W0-2 .. W0+131
        int l = W0 - 2 + tid;
        float a = (l >= 0 && l < 1024) ? x[b * 1024 + l] : 0.f;
        float s, c; sincosf(a, &s, &c);
        xcs[tid] = make_float2(c, s);
    }
    if (tid >= 128) {                  // threads 128..255 -> dwc[0..127] (FULL cover)
        int wl = tid - 128;
        int widx = W0 + wl;
        dwc[wl] = (widx < 1022) ? dw[widx] : 0.f;
    }
    __syncthreads();

    // phase 1: G build (validated R6 k_g formula). e = q*116 + u*4 + comp,
    // t = u + 27*comp; G_q[t] = (1/16) sum over 16 consistent (i,j) of +-H.
    for (int e = tid; e < 928; e += 256) {
        int q = e / GSTRIDE, rem = e - q * GSTRIDE;
        int u = rem >> 2, comp = rem & 3;
        float val = 0.f;
        if (u < 27 && comp < 3) {
            int t = u + 27 * comp;
            int td_[4] = {t % 3, (t / 3) % 3, (t / 9) % 3, t / 27};
            float acc = 0.f;
            for (int cb = 0; cb < 16; ++cb) {
                int i = 0, j = 0; float sgn = 1.f;
#pragma unroll
                for (int k = 0; k < 4; ++k) {
                    int bk = (cb >> k) & 1;
                    if (td_[k] == 2) { i |= bk << k; j |= (1 - bk) << k; }
                    else { i |= bk << k; j |= bk << k;
                           if (td_[k] == 1 && bk) sgn = -sgn; }
                }
                acc += sgn * Hs[q * 256 + i * 16 + j];
            }
            val = acc * 0.0625f;
        }
        Gs[e] = val;                    // pad entries written too (defensive)
    }
    __syncthreads();

    // phase 2: y1 halo, s = W0-1+tid for tid<131; uses xcs[tid..tid+3]
    if (tid < 131) {
        int s = W0 - 1 + tid;
        float y = 0.f;
        if (s >= 0 && s < 1023) {
            float2 f0 = xcs[tid], f1 = xcs[tid + 1], f2 = xcs[tid + 2], f3 = xcs[tid + 3];
            const float4* T0 = (const float4*)Gs;
            float l3[27];
#pragma unroll
            for (int u = 0; u < 27; ++u) {
                float4 g = T0[u];
                l3[u] = fmaf(g.z, f3.y, fmaf(g.y, f3.x, g.x));
            }
            float l2[9];
#pragma unroll
            for (int u = 0; u < 9; ++u)
                l2[u] = fmaf(l3[u + 18], f2.y, fmaf(l3[u + 9], f2.x, l3[u]));
            float l1[3];
#pragma unroll
            for (int u = 0; u < 3; ++u)
                l1[u] = fmaf(l2[u + 6], f1.y, fmaf(l2[u + 3], f1.x, l2[u]));
            y = fmaf(l1[2], f0.y, fmaf(l1[1], f0.x, l1[0]));
            y = fmaxf(y, 0.f);         // relu
        }
        float s_, c_; sincosf(y, &s_, &c_);
        ycs[tid] = make_float2(c_, s_);    // y=0 -> (1,0) = zero-pad
    }
    __syncthreads();

    // phase 3: 4 windows per lane; q = tid&7, wl = (tid>>3) + 32*w4
    int q = tid & 7, wbase = tid >> 3;
    const float4* Tq = (const float4*)&Gs[q * GSTRIDE];
    float2 F0[4], F1[4], F2[4], F3[4];
#pragma unroll
    for (int w4 = 0; w4 < 4; ++w4) {
        int wl = wbase + 32 * w4;
        F0[w4] = ycs[wl];     F1[w4] = ycs[wl + 1];
        F2[w4] = ycs[wl + 2]; F3[w4] = ycs[wl + 3];
    }
    float l3[4][27];
#pragma unroll
    for (int u = 0; u < 27; ++u) {
        float4 g = Tq[u];
#pragma unroll
        for (int w4 = 0; w4 < 4; ++w4)
            l3[w4][u] = fmaf(g.z, F3[w4].y, fmaf(g.y, F3[w4].x, g.x));
    }
    float contrib = 0.f;
#pragma unroll
    for (int w4 = 0; w4 < 4; ++w4) {
        float l2[9];
#pragma unroll
        for (int u = 0; u < 9; ++u)
            l2[u] = fmaf(l3[w4][u + 18], F2[w4].y, fmaf(l3[w4][u + 9], F2[w4].x, l3[w4][u]));
        float l1[3];
#pragma unroll
        for (int u = 0; u < 3; ++u)
            l1[u] = fmaf(l2[u + 6], F1[w4].y, fmaf(l2[u + 3], F1[w4].x, l2[u]));
        float yq = fmaf(l1[2], F0[w4].y, fmaf(l1[1], F0[w4].x, l1[0]));
        // max over the 8 q-lanes of this window
        yq = fmaxf(yq, __shfl_xor(yq, 1));
        yq = fmaxf(yq, __shfl_xor(yq, 2));
        yq = fmaxf(yq, __shfl_xor(yq, 4));
        if (q == 0) {
            int wl = wbase + 32 * w4;
            contrib = fmaf(fmaxf(yq, 0.f), dwc[wl], contrib);  // dwc=0 if widx>=1022
        }
    }
    // wave sum (non-q0 lanes hold 0), then cross-wave combine
#pragma unroll
    for (int off = 1; off <= 32; off <<= 1) contrib += __shfl_xor(contrib, off);
    if ((tid & 63) == 0) red[tid >> 6] = contrib;
    __syncthreads();
    if (tid == 0)
        atomicAdd(&out[b], (red[0] + red[1]) + (red[2] + red[3]));
}

extern "C" void kernel_launch(void* const* d_in, const int* in_sizes, int n_in,
                              void* d_out, int out_size, void* d_ws, size_t ws_size,
                              hipStream_t stream) {
    const float* x  = (const float*)d_in[0];   // (32,1024,1)
    const float* wt = (const float*)d_in[1];   // (3,8)
    const float* dw = (const float*)d_in[2];   // (1022,1)
    const float* db = (const float*)d_in[3];   // (1,)
    float* H   = (float*)d_ws;                 // 2048 floats
    float* out = (float*)d_out;

    hipLaunchKernelGGL(k_simh, dim3(256), dim3(64),  0, stream, wt, H, db, out);
    hipLaunchKernelGGL(k_main, dim3(256), dim3(256), 0, stream, x, H, dw, out);
}

// Round 9
// 21.971 us; speedup vs baseline: 2.5567x; 1.0300x over previous
//
#include <hip/hip_runtime.h>
#include <math.h>

#define TWO_PI 6.2831853071795864769f

// ws layout (floats): [0, 2048) H: 8 q x 16 x 16.  (everything else in-kernel)

// ---------------------------------------------------------------------------
// Register-resident statevector sim, one wave simulates TWO states.
// Lane owns amps k = lane*4+r: k bit p (p>=2) == lane bit (p-2), k bits 1,0
// == reg index. Qubit q lives at bit position p = 7-q.
// Per-wire fusion (one cross-lane round per wire), validated R6/R8 (absmax 0.0):
//  j<7:  (CNOT RY CNOT) RX: 4-term gather, masks pcb, pcb|ptb, ptb
//  j=7:  fully register-local
// ---------------------------------------------------------------------------

__device__ __forceinline__ float2 shflx2(float2 a, int m) {
    return make_float2(__shfl_xor(a.x, m), __shfl_xor(a.y, m));
}

__device__ __forceinline__ void fused4(float2 v[4], int lane, int pcb, int ptb,
                                       float a2, float bb, float d2) {
    int M = pcb | ptb;
    int l1 = pcb >> 2, r1 = pcb & 3;
    int l2 = M >> 2,   r2 = M & 3;
    int l3 = ptb >> 2, r3 = ptb & 3;
    float2 o1[4], o2[4], o3[4];
#pragma unroll
    for (int r = 0; r < 4; ++r) {
        float2 s1 = v[r ^ r1]; o1[r] = l1 ? shflx2(s1, l1) : s1;
        float2 s2 = v[r ^ r2]; o2[r] = l2 ? shflx2(s2, l2) : s2;
        float2 s3 = v[r ^ r3]; o3[r] = l3 ? shflx2(s3, l3) : s3;
    }
#pragma unroll
    for (int r = 0; r < 4; ++r) {
        int k = (lane << 2) | r;
        float sA = (k & pcb) ? 1.f : -1.f;
        float bs = bb * sA, ds = d2 * sA;
        float nx = fmaf(a2, v[r].x, fmaf(bb, o1[r].y, fmaf(bs, o2[r].x,  ds * o3[r].y)));
        float ny = fmaf(a2, v[r].y, fmaf(-bb, o1[r].x, fmaf(bs, o2[r].y, -ds * o3[r].x)));
        v[r] = make_float2(nx, ny);
    }
}

__device__ __forceinline__ void wire7(float2 v[4], int lane, float a2, float bb, float d2) {
    float2 o[4];
#pragma unroll
    for (int r = 0; r < 4; ++r) o[r] = v[r ^ 1];
#pragma unroll
    for (int r = 0; r < 4; ++r) {
        int k = (lane << 2) | r;
        float s7 = (((k >> 7) ^ k) & 1) ? 1.f : -1.f;
        float Ax = a2, Ay = -d2 * s7, Bx = bb * s7, By = -bb;
        float nx = fmaf(Ax, v[r].x, fmaf(-Ay, v[r].y, fmaf(Bx, o[r].x, -By * o[r].y)));
        float ny = fmaf(Ax, v[r].y, fmaf( Ay, v[r].x, fmaf(Bx, o[r].y,  By * o[r].x)));
        v[r] = make_float2(nx, ny);
    }
}

__device__ __forceinline__ void rz2(float2 v[4], float2 u[4], int lane, int p,
                                    float ch, float sh) {
#pragma unroll
    for (int r = 0; r < 4; ++r) {
        int k = (lane << 2) | r;
        float s = ((k >> p) & 1) ? sh : -sh;
        v[r] = make_float2(fmaf(ch, v[r].x, -s * v[r].y),
                           fmaf(ch, v[r].y, s * v[r].x));
        u[r] = make_float2(fmaf(ch, u[r].x, -s * u[r].y),
                           fmaf(ch, u[r].y, s * u[r].x));
    }
}

__device__ __forceinline__ void ansatz2(float2 v[4], float2 u[4],
                                        const float* chs, const float* shs, int lane) {
#pragma unroll
    for (int j = 0; j < 7; ++j) {
        float ch = chs[j], sh = shs[j];
        float a2 = ch * ch, bb = ch * sh, d2 = sh * sh;
        int pcb = 1 << (7 - j), ptb = 1 << (6 - j);
        fused4(v, lane, pcb, ptb, a2, bb, d2);
        fused4(u, lane, pcb, ptb, a2, bb, d2);
        rz2(v, u, lane, 7 - j, ch, sh);
    }
    {
        float ch = chs[7], sh = shs[7];
        float a2 = ch * ch, bb = ch * sh, d2 = sh * sh;
        wire7(v, lane, a2, bb, d2);
        wire7(u, lane, a2, bb, d2);
        rz2(v, u, lane, 0, ch, sh);
    }
}

__device__ __forceinline__ void applyB(float2 v[4], int S, int lane) {
    int sbits = ((S & 1) << 7) | ((S & 2) << 5) | ((S & 4) << 3) | ((S & 8) << 1);
    int m = sbits >> 2;
    float2 nv[4];
#pragma unroll
    for (int r = 0; r < 4; ++r) {
        float2 o = shflx2(v[r], m);
        int k = (lane << 2) | r;
        float sg = (__popc(sbits & ~k) & 1) ? -1.f : 1.f;
        nv[r] = make_float2(sg * o.x, sg * o.y);
    }
#pragma unroll
    for (int r = 0; r < 4; ++r) v[r] = nv[r];
}

// K1: block (i,j) simulates phi_i and phi_j, emits H_q[i][j] for all 8 q.
// Block 0 also initializes out[b] = bias (k_main atomically accumulates).
__global__ __launch_bounds__(64) void k_simh(const float* wt, float* H,
                                             const float* db, float* out) {
    __shared__ float chs[24], shs[24];
    int lane = threadIdx.x;
    if (lane < 24) {
        float th = wt[lane];
        th = th - floorf(th / TWO_PI) * TWO_PI;   // jnp.mod(w, 2pi)
        float s, c;
        sincosf(0.5f * th, &s, &c);
        chs[lane] = c; shs[lane] = s;
    }
    if (blockIdx.x == 0 && lane < 32) out[lane] = db[0];
    __syncthreads();

    int i = blockIdx.x >> 4, j = blockIdx.x & 15;
    float2 v[4], u[4];
#pragma unroll
    for (int r = 0; r < 4; ++r) {
        v[r] = make_float2(0.f, 0.f);
        u[r] = make_float2(0.f, 0.f);
    }
    if (lane == 0) { v[0] = make_float2(1.f, 0.f); u[0] = make_float2(1.f, 0.f); }

    ansatz2(v, u, chs, shs, lane);
    applyB(v, i, lane);
    applyB(u, j, lane);
    ansatz2(v, u, chs + 8, shs + 8, lane);
    ansatz2(v, u, chs + 16, shs + 16, lane);

    float acc[8] = {0.f, 0.f, 0.f, 0.f, 0.f, 0.f, 0.f, 0.f};
#pragma unroll
    for (int r = 0; r < 4; ++r) {
        int k = (lane << 2) | r;
        float p = v[r].x * u[r].x + v[r].y * u[r].y;
#pragma unroll
        for (int q = 0; q < 8; ++q)
            acc[q] += ((k >> (7 - q)) & 1) ? -p : p;
    }
#pragma unroll
    for (int q = 0; q < 8; ++q) {
#pragma unroll
        for (int off = 32; off >= 1; off >>= 1)
            acc[q] += __shfl_xor(acc[q], off);
    }
    if (lane == 0) {
#pragma unroll
        for (int q = 0; q < 8; ++q)
            H[q * 256 + i * 16 + j] = acc[q];
    }
}

// ---------------------------------------------------------------------------
// K2: everything else, one block per (b, segment-of-128-windows), 512 threads
// (8 waves -> 2 waves/SIMD for latency hiding).
// Phases: load H + x-halo sincos + dw slice | build G in LDS | y1 halo (131)
// | 2 windows per lane, G reads hoisted to registers | pool + dense + atomic.
// G row stride 116 floats: b128 reads at (q*20 + u*4) mod 32 -> conflict-free.
// ---------------------------------------------------------------------------
#define GSTRIDE 116

__global__ __launch_bounds__(512, 1) void k_main(const float* x, const float* H,
                                                 const float* dw, float* out) {
    __shared__ __align__(16) float Hs[2048];
    __shared__ __align__(16) float Gs[8 * GSTRIDE];   // 928 floats
    __shared__ float2 xcs[134];
    __shared__ float2 ycs[131];
    __shared__ float dwc[128];
    __shared__ float red[8];
    int tid = threadIdx.x;
    int b = blockIdx.x >> 3, seg = blockIdx.x & 7;
    int W0 = seg << 7;                 // first window of this segment

    // phase 0: H -> LDS (1 float4/thread), x halo sincos, dw slice
    ((float4*)Hs)[tid] = ((const float4*)H)[tid];
    if (tid < 134) {                   // x positions l = W0-2 .. W0+131
        int l = W0 - 2 + tid;
        float a = (l >= 0 && l < 1024) ? x[b * 1024 + l] : 0.f;
        float s, c; sincosf(a, &s, &c);
        xcs[tid] = make_float2(c, s);
    }
    if (tid >= 384) {                  // threads 384..511 -> dwc[0..127] (full cover)
        int wl = tid - 384;
        int widx = W0 + wl;
        dwc[wl] = (widx < 1022) ? dw[widx] : 0.f;
    }
    __syncthreads();

    // phase 1: G build (validated R6/R8 formula). e = q*116 + u*4 + comp,
    // t = u + 27*comp; G_q[t] = (1/16) sum over 16 consistent (i,j) of +-H.
    for (int e = tid; e < 928; e += 512) {
        int q = e / GSTRIDE, rem = e - q * GSTRIDE;
        int u = rem >> 2, comp = rem & 3;
        float val = 0.f;
        if (u < 27 && comp < 3) {
            int t = u + 27 * comp;
            int td_[4] = {t % 3, (t / 3) % 3, (t / 9) % 3, t / 27};
            float acc = 0.f;
            for (int cb = 0; cb < 16; ++cb) {
                int i = 0, j = 0; float sgn = 1.f;
#pragma unroll
                for (int k = 0; k < 4; ++k) {
                    int bk = (cb >> k) & 1;
                    if (td_[k] == 2) { i |= bk << k; j |= (1 - bk) << k; }
                    else { i |= bk << k; j |= bk << k;
                           if (td_[k] == 1 && bk) sgn = -sgn; }
                }
                acc += sgn * Hs[q * 256 + i * 16 + j];
            }
            val = acc * 0.0625f;
        }
        Gs[e] = val;                   // pad entries written too (defensive)
    }
    __syncthreads();

    // phase 2: y1 halo, s = W0-1+tid for tid<131; uses xcs[tid..tid+3]
    if (tid < 131) {
        int s = W0 - 1 + tid;
        float y = 0.f;
        if (s >= 0 && s < 1023) {
            float2 f0 = xcs[tid], f1 = xcs[tid + 1], f2 = xcs[tid + 2], f3 = xcs[tid + 3];
            const float4* T0 = (const float4*)Gs;
            float l3[27];
#pragma unroll
            for (int u = 0; u < 27; ++u) {
                float4 g = T0[u];
                l3[u] = fmaf(g.z, f3.y, fmaf(g.y, f3.x, g.x));
            }
            float l2[9];
#pragma unroll
            for (int u = 0; u < 9; ++u)
                l2[u] = fmaf(l3[u + 18], f2.y, fmaf(l3[u + 9], f2.x, l3[u]));
            float l1[3];
#pragma unroll
            for (int u = 0; u < 3; ++u)
                l1[u] = fmaf(l2[u + 6], f1.y, fmaf(l2[u + 3], f1.x, l2[u]));
            y = fmaf(l1[2], f0.y, fmaf(l1[1], f0.x, l1[0]));
            y = fmaxf(y, 0.f);         // relu
        }
        float s_, c_; sincosf(y, &s_, &c_);
        ycs[tid] = make_float2(c_, s_);    // y=0 -> (1,0) = zero-pad
    }
    __syncthreads();

    // phase 3: 2 windows per lane; q = tid&7, wl = (tid>>3) + 64*w2
    int q = tid & 7, wbase = tid >> 3;     // wbase in [0,64)
    const float4* Tq = (const float4*)&Gs[q * GSTRIDE];
    float2 F0[2], F1[2], F2[2], F3[2];
#pragma unroll
    for (int w2 = 0; w2 < 2; ++w2) {
        int wl = wbase + 64 * w2;
        F0[w2] = ycs[wl];     F1[w2] = ycs[wl + 1];
        F2[w2] = ycs[wl + 2]; F3[w2] = ycs[wl + 3];
    }
    float l3[2][27];
#pragma unroll
    for (int u = 0; u < 27; ++u) {
        float4 g = Tq[u];
#pragma unroll
        for (int w2 = 0; w2 < 2; ++w2)
            l3[w2][u] = fmaf(g.z, F3[w2].y, fmaf(g.y, F3[w2].x, g.x));
    }
    float contrib = 0.f;
#pragma unroll
    for (int w2 = 0; w2 < 2; ++w2) {
        float l2[9];
#pragma unroll
        for (int u = 0; u < 9; ++u)
            l2[u] = fmaf(l3[w2][u + 18], F2[w2].y, fmaf(l3[w2][u + 9], F2[w2].x, l3[w2][u]));
        float l1[3];
#pragma unroll
        for (int u = 0; u < 3; ++u)
            l1[u] = fmaf(l2[u + 6], F1[w2].y, fmaf(l2[u + 3], F1[w2].x, l2[u]));
        float yq = fmaf(l1[2], F0[w2].y, fmaf(l1[1], F0[w2].x, l1[0]));
        // max over the 8 q-lanes of this window
        yq = fmaxf(yq, __shfl_xor(yq, 1));
        yq = fmaxf(yq, __shfl_xor(yq, 2));
        yq = fmaxf(yq, __shfl_xor(yq, 4));
        if (q == 0) {
            int wl = wbase + 64 * w2;
            contrib = fmaf(fmaxf(yq, 0.f), dwc[wl], contrib);  // dwc=0 if widx>=1022
        }
    }
    // wave sum (non-q0 lanes hold 0), then cross-wave combine
#pragma unroll
    for (int off = 1; off <= 32; off <<= 1) contrib += __shfl_xor(contrib, off);
    if ((tid & 63) == 0) red[tid >> 6] = contrib;
    __syncthreads();
    if (tid == 0) {
        float s = ((red[0] + red[1]) + (red[2] + red[3]))
                + ((red[4] + red[5]) + (red[6] + red[7]));
        atomicAdd(&out[b], s);
    }
}

extern "C" void kernel_launch(void* const* d_in, const int* in_sizes, int n_in,
                              void* d_out, int out_size, void* d_ws, size_t ws_size,
                              hipStream_t stream) {
    const float* x  = (const float*)d_in[0];   // (32,1024,1)
    const float* wt = (const float*)d_in[1];   // (3,8)
    const float* dw = (const float*)d_in[2];   // (1022,1)
    const float* db = (const float*)d_in[3];   // (1,)
    float* H   = (float*)d_ws;                 // 2048 floats
    float* out = (float*)d_out;

    hipLaunchKernelGGL(k_simh, dim3(256), dim3(64),  0, stream, wt, H, db, out);
    hipLaunchKernelGGL(k_main, dim3(256), dim3(512), 0, stream, x, H, dw, out);
}